// Round 1
// baseline (371.026 us; speedup 1.0000x reference)
//
#include <hip/hip_runtime.h>
#include <math.h>

#define NB 1024      // batch (queries)
#define NP 512       // pool size
#define NH 1024      // hidden
#define NK 8         // topk
#define NL 32        // pre_seq_len
#define EPSF 1e-8f

// ---------------- Kernel 1: inverse norms (1/max(||row||, eps)) ----------------
__global__ __launch_bounds__(256) void norms_kernel(
    const float* __restrict__ q, const float* __restrict__ pk,
    float* __restrict__ qinv, float* __restrict__ kinv) {
  int row = blockIdx.x * 4 + (threadIdx.x >> 6);
  int lane = threadIdx.x & 63;
  const float* src;
  float* dst;
  if (row < NB) {
    src = q + (size_t)row * NH;
    dst = qinv + row;
  } else {
    int r = row - NB;
    if (r >= NP) return;
    src = pk + (size_t)r * NH;
    dst = kinv + r;
  }
  const float4* v = (const float4*)src;
  float s = 0.f;
#pragma unroll
  for (int i = 0; i < (NH / 4) / 64; ++i) {   // 1024/4/64 = 4 float4 per lane
    float4 x = v[lane + i * 64];
    s += x.x * x.x + x.y * x.y + x.z * x.z + x.w * x.w;
  }
#pragma unroll
  for (int off = 32; off; off >>= 1) s += __shfl_xor(s, off);
  if (lane == 0) *dst = 1.f / fmaxf(sqrtf(s), EPSF);
}

// ---------------- Kernel 2: sim[b][p] = qn(b) . kn(p), tiled fp32 GEMM ----------------
// Block: 256 threads = 16x16, each thread computes 2x2 outputs of a 32x32 tile.
__global__ __launch_bounds__(256) void sim_kernel(
    const float* __restrict__ q, const float* __restrict__ pk,
    const float* __restrict__ qinv, const float* __restrict__ kinv,
    float* __restrict__ sim) {
  __shared__ float As[32][33];  // +1 pad: conflict-free reads
  __shared__ float Bs[32][33];
  const int bm = blockIdx.x;  // query tile  (32 tiles)
  const int bn = blockIdx.y;  // pool tile   (16 tiles)
  const int tid = threadIdx.x;
  const int tx = tid & 15;    // 0..15 -> pool cols 2*tx+{0,1}
  const int ty = tid >> 4;    // 0..15 -> query rows 2*ty+{0,1}
  const int lrow = tid >> 3;          // 0..31 (load row)
  const int lcol = (tid & 7) * 4;     // 0,4,...,28 (load col, float4)

  float acc00 = 0.f, acc01 = 0.f, acc10 = 0.f, acc11 = 0.f;

  const float* qrow = q + (size_t)(bm * 32 + lrow) * NH + lcol;
  const float* krow = pk + (size_t)(bn * 32 + lrow) * NH + lcol;

  for (int kt = 0; kt < NH; kt += 32) {
    float4 a = *(const float4*)(qrow + kt);
    float4 b = *(const float4*)(krow + kt);
    __syncthreads();  // protect previous iteration's readers
    As[lrow][lcol + 0] = a.x; As[lrow][lcol + 1] = a.y;
    As[lrow][lcol + 2] = a.z; As[lrow][lcol + 3] = a.w;
    Bs[lrow][lcol + 0] = b.x; Bs[lrow][lcol + 1] = b.y;
    Bs[lrow][lcol + 2] = b.z; Bs[lrow][lcol + 3] = b.w;
    __syncthreads();
#pragma unroll
    for (int k = 0; k < 32; ++k) {
      float a0 = As[2 * ty + 0][k];
      float a1 = As[2 * ty + 1][k];
      float b0 = Bs[2 * tx + 0][k];
      float b1 = Bs[2 * tx + 1][k];
      acc00 += a0 * b0; acc01 += a0 * b1;
      acc10 += a1 * b0; acc11 += a1 * b1;
    }
  }

  const int r0 = bm * 32 + 2 * ty;
  const int c0 = bn * 32 + 2 * tx;
  const float qi0 = qinv[r0], qi1 = qinv[r0 + 1];
  const float ki0 = kinv[c0], ki1 = kinv[c0 + 1];
  sim[(size_t)(r0 + 0) * NP + c0 + 0] = acc00 * qi0 * ki0;
  sim[(size_t)(r0 + 0) * NP + c0 + 1] = acc01 * qi0 * ki1;
  sim[(size_t)(r0 + 1) * NP + c0 + 0] = acc10 * qi1 * ki0;
  sim[(size_t)(r0 + 1) * NP + c0 + 1] = acc11 * qi1 * ki1;
}

// ---------------- Kernel 3: per-row top-8 (sorted desc, tie -> lower index) ----------------
// One wave (64 lanes) per query row; each lane owns 8 candidates (512/64).
__global__ __launch_bounds__(256) void topk_kernel(
    const float* __restrict__ sim, float* __restrict__ top_sim, int* __restrict__ top_idx) {
  int row = blockIdx.x * 4 + (threadIdx.x >> 6);
  int lane = threadIdx.x & 63;
  if (row >= NB) return;

  float vals[NP / 64];
#pragma unroll
  for (int i = 0; i < NP / 64; ++i) vals[i] = sim[(size_t)row * NP + lane + i * 64];

  for (int t = 0; t < NK; ++t) {
    // local argmax (ascending global index order -> strict > keeps lowest idx)
    float bv = vals[0];
    int bi = 0;
#pragma unroll
    for (int i = 1; i < NP / 64; ++i) {
      if (vals[i] > bv) { bv = vals[i]; bi = i; }
    }
    float v = bv;
    int p = lane + bi * 64;
    // wave argmax butterfly, tie -> smaller global index
#pragma unroll
    for (int off = 32; off; off >>= 1) {
      float ov = __shfl_xor(v, off);
      int op = __shfl_xor(p, off);
      if (ov > v || (ov == v && op < p)) { v = ov; p = op; }
    }
    if (lane == 0) {
      top_sim[row * NK + t] = v;
      top_idx[row * NK + t] = p;
    }
    // mask out the winner on its owning lane (static indexing to stay in regs)
    if ((p & 63) == lane) {
      int wi = p >> 6;
#pragma unroll
      for (int i = 0; i < NP / 64; ++i)
        if (i == wi) vals[i] = -INFINITY;
    }
  }
}

// ---------------- Kernel 4a: gather slices 0..8190 ----------------
// One block per (b,k); copies 32*1024 floats = 8192 float4 with 256 threads.
__global__ __launch_bounds__(256) void gather_main(
    const float* __restrict__ prompts, const int* __restrict__ idx,
    float* __restrict__ out) {
  const int bk = blockIdx.x;  // 0..8190 — none of these slices contain idx[]
  const int p = idx[bk];
  const float4* __restrict__ src = (const float4*)(prompts + (size_t)p * (NL * NH));
  float4* __restrict__ dst = (float4*)(out + (size_t)bk * (NL * NH));
  const int t = threadIdx.x;
#pragma unroll
  for (int i = 0; i < (NL * NH / 4) / 256; ++i) {  // 32 float4 per thread
    dst[t + i * 256] = src[t + i * 256];
  }
}

// ---------------- Kernel 4b: gather slice 8191 (contains the idx scratch) ----------------
// Single block: read idx first, barrier, then overwrite the slice.
__global__ __launch_bounds__(256) void gather_last(
    const float* __restrict__ prompts, const int* __restrict__ idx,
    float* __restrict__ out) {
  const int bk = NB * NK - 1;
  const int p = idx[bk];
  __syncthreads();  // all reads of idx complete before any write below
  const float4* __restrict__ src = (const float4*)(prompts + (size_t)p * (NL * NH));
  float4* __restrict__ dst = (float4*)(out + (size_t)bk * (NL * NH));
  const int t = threadIdx.x;
#pragma unroll
  for (int i = 0; i < (NL * NH / 4) / 256; ++i) {
    dst[t + i * 256] = src[t + i * 256];
  }
}

extern "C" void kernel_launch(void* const* d_in, const int* in_sizes, int n_in,
                              void* d_out, int out_size, void* d_ws, size_t ws_size,
                              hipStream_t stream) {
  const float* querys = (const float*)d_in[0];       // [1024,1024]
  const float* prompts_key = (const float*)d_in[1];  // [512,1024]
  const float* prompts = (const float*)d_in[2];      // [512,32,1024]
  float* out = (float*)d_out;

  const size_t GATHER = (size_t)NB * NK * NL * NH;  // 268435456 floats
  float* top_sim = out + GATHER;                    // final output tail [1024*8]

  // Scratch carved from the gather region of d_out (no d_ws assumptions):
  //  - sim / qinv / kinv at the front: fully consumed by topk (stream-ordered)
  //    before gather overwrites them.
  //  - idx in the LAST 8192 floats: that lies only inside slice bk=8191, which
  //    is written by gather_last (a single block that reads-then-barriers).
  float* sim = out;                             // [1024*512] = 2 MiB
  float* qinv = out + (size_t)NB * NP;          // [1024]
  float* kinv = qinv + NB;                      // [512]
  int* idx = (int*)(out + GATHER - (size_t)NB * NK);  // [8192] ints

  norms_kernel<<<(NB + NP) / 4, 256, 0, stream>>>(querys, prompts_key, qinv, kinv);

  dim3 gsim(NB / 32, NP / 32);  // 32 x 16
  sim_kernel<<<gsim, 256, 0, stream>>>(querys, prompts_key, qinv, kinv, sim);

  topk_kernel<<<NB / 4, 256, 0, stream>>>(sim, top_sim, idx);

  gather_main<<<NB * NK - 1, 256, 0, stream>>>(prompts, idx, out);
  gather_last<<<1, 256, 0, stream>>>(prompts, idx, out);
}

// Round 2
// 363.032 us; speedup vs baseline: 1.0220x; 1.0220x over previous
//
#include <hip/hip_runtime.h>
#include <math.h>

#define NB 1024      // batch (queries)
#define NP 512       // pool size
#define NH 1024      // hidden
#define NK 8         // topk
#define NL 32        // pre_seq_len
#define EPSF 1e-8f

typedef float f32x4 __attribute__((ext_vector_type(4)));

// ---------------- Kernel 1: inverse norms (1/max(||row||, eps)) ----------------
__global__ __launch_bounds__(256) void norms_kernel(
    const float* __restrict__ q, const float* __restrict__ pk,
    float* __restrict__ qinv, float* __restrict__ kinv) {
  int row = blockIdx.x * 4 + (threadIdx.x >> 6);
  int lane = threadIdx.x & 63;
  const float* src;
  float* dst;
  if (row < NB) {
    src = q + (size_t)row * NH;
    dst = qinv + row;
  } else {
    int r = row - NB;
    if (r >= NP) return;
    src = pk + (size_t)r * NH;
    dst = kinv + r;
  }
  const float4* v = (const float4*)src;
  float s = 0.f;
#pragma unroll
  for (int i = 0; i < (NH / 4) / 64; ++i) {   // 4 float4 per lane
    float4 x = v[lane + i * 64];
    s += x.x * x.x + x.y * x.y + x.z * x.z + x.w * x.w;
  }
#pragma unroll
  for (int off = 32; off; off >>= 1) s += __shfl_xor(s, off);
  if (lane == 0) *dst = 1.f / fmaxf(sqrtf(s), EPSF);
}

// ---------------- Kernel 2: sim[b][p] = qn(b) . kn(p), tiled fp32 GEMM ----------------
// Block: 256 threads = 16x16, each thread computes 2x2 of a 32x32 tile.
// LDS stored TRANSPOSED [k][m] (stride 34) so fragment reads are ds_read_b64.
__global__ __launch_bounds__(256) void sim_kernel(
    const float* __restrict__ q, const float* __restrict__ pk,
    const float* __restrict__ qinv, const float* __restrict__ kinv,
    float* __restrict__ sim) {
  __shared__ float As[32][34];  // [k][m]; stride 34: even (b64 align) + 2-way-free banks
  __shared__ float Bs[32][34];  // [k][n]
  const int bm = blockIdx.x;  // query tile  (32 tiles)
  const int bn = blockIdx.y;  // pool tile   (16 tiles)
  const int tid = threadIdx.x;
  const int tx = tid & 15;    // pool cols 2*tx+{0,1}
  const int ty = tid >> 4;    // query rows 2*ty+{0,1}
  const int lrow = tid >> 3;          // 0..31 (m/n index of the load)
  const int lcol = (tid & 7) * 4;     // 0..28 step 4 (k index of the load)

  float acc00 = 0.f, acc01 = 0.f, acc10 = 0.f, acc11 = 0.f;

  const float* qrow = q + (size_t)(bm * 32 + lrow) * NH + lcol;
  const float* krow = pk + (size_t)(bn * 32 + lrow) * NH + lcol;

  for (int kt = 0; kt < NH; kt += 32) {
    float4 a = *(const float4*)(qrow + kt);
    float4 b = *(const float4*)(krow + kt);
    __syncthreads();  // protect previous iteration's readers
    As[lcol + 0][lrow] = a.x; As[lcol + 1][lrow] = a.y;
    As[lcol + 2][lrow] = a.z; As[lcol + 3][lrow] = a.w;
    Bs[lcol + 0][lrow] = b.x; Bs[lcol + 1][lrow] = b.y;
    Bs[lcol + 2][lrow] = b.z; Bs[lcol + 3][lrow] = b.w;
    __syncthreads();
#pragma unroll
    for (int k = 0; k < 32; ++k) {
      float2 a01 = *(const float2*)&As[k][2 * ty];  // one ds_read_b64
      float2 b01 = *(const float2*)&Bs[k][2 * tx];  // one ds_read_b64
      acc00 += a01.x * b01.x; acc01 += a01.x * b01.y;
      acc10 += a01.y * b01.x; acc11 += a01.y * b01.y;
    }
  }

  const int r0 = bm * 32 + 2 * ty;
  const int c0 = bn * 32 + 2 * tx;
  const float qi0 = qinv[r0], qi1 = qinv[r0 + 1];
  const float ki0 = kinv[c0], ki1 = kinv[c0 + 1];
  sim[(size_t)(r0 + 0) * NP + c0 + 0] = acc00 * qi0 * ki0;
  sim[(size_t)(r0 + 0) * NP + c0 + 1] = acc01 * qi0 * ki1;
  sim[(size_t)(r0 + 1) * NP + c0 + 0] = acc10 * qi1 * ki0;
  sim[(size_t)(r0 + 1) * NP + c0 + 1] = acc11 * qi1 * ki1;
}

// ---------------- Kernel 3: per-row top-8 (sorted desc, tie -> lower index) ----------------
__global__ __launch_bounds__(256) void topk_kernel(
    const float* __restrict__ sim, float* __restrict__ top_sim, int* __restrict__ top_idx) {
  int row = blockIdx.x * 4 + (threadIdx.x >> 6);
  int lane = threadIdx.x & 63;
  if (row >= NB) return;

  float vals[NP / 64];
#pragma unroll
  for (int i = 0; i < NP / 64; ++i) vals[i] = sim[(size_t)row * NP + lane + i * 64];

  for (int t = 0; t < NK; ++t) {
    float bv = vals[0];
    int bi = 0;
#pragma unroll
    for (int i = 1; i < NP / 64; ++i) {
      if (vals[i] > bv) { bv = vals[i]; bi = i; }
    }
    float v = bv;
    int p = lane + bi * 64;
#pragma unroll
    for (int off = 32; off; off >>= 1) {
      float ov = __shfl_xor(v, off);
      int op = __shfl_xor(p, off);
      if (ov > v || (ov == v && op < p)) { v = ov; p = op; }
    }
    if (lane == 0) {
      top_sim[row * NK + t] = v;
      top_idx[row * NK + t] = p;
    }
    if ((p & 63) == lane) {
      int wi = p >> 6;
#pragma unroll
      for (int i = 0; i < NP / 64; ++i)
        if (i == wi) vals[i] = -INFINITY;
    }
  }
}

// ---------------- Kernel 4a: gather slices 0..8190 (non-temporal stores) ----------------
__global__ __launch_bounds__(256) void gather_main(
    const float* __restrict__ prompts, const int* __restrict__ idx,
    float* __restrict__ out) {
  const int bk = blockIdx.x;  // 0..8190 — none of these slices contain idx[]
  const int p = idx[bk];
  const f32x4* __restrict__ src = (const f32x4*)(prompts + (size_t)p * (NL * NH));
  f32x4* __restrict__ dst = (f32x4*)(out + (size_t)bk * (NL * NH));
  const int t = threadIdx.x;
#pragma unroll
  for (int i = 0; i < (NL * NH / 4) / 256; ++i) {  // 32 float4 per thread
    f32x4 v = src[t + i * 256];                    // cached read (pool is L3-resident)
    __builtin_nontemporal_store(v, &dst[t + i * 256]);  // nt write: don't evict the pool
  }
}

// ---------------- Kernel 4b: gather slice 8191 (contains the idx scratch) ----------------
__global__ __launch_bounds__(256) void gather_last(
    const float* __restrict__ prompts, const int* __restrict__ idx,
    float* __restrict__ out) {
  const int bk = NB * NK - 1;
  const int p = idx[bk];
  __syncthreads();  // all reads of idx complete before any write below
  const f32x4* __restrict__ src = (const f32x4*)(prompts + (size_t)p * (NL * NH));
  f32x4* __restrict__ dst = (f32x4*)(out + (size_t)bk * (NL * NH));
  const int t = threadIdx.x;
#pragma unroll
  for (int i = 0; i < (NL * NH / 4) / 256; ++i) {
    f32x4 v = src[t + i * 256];
    __builtin_nontemporal_store(v, &dst[t + i * 256]);
  }
}

extern "C" void kernel_launch(void* const* d_in, const int* in_sizes, int n_in,
                              void* d_out, int out_size, void* d_ws, size_t ws_size,
                              hipStream_t stream) {
  const float* querys = (const float*)d_in[0];       // [1024,1024]
  const float* prompts_key = (const float*)d_in[1];  // [512,1024]
  const float* prompts = (const float*)d_in[2];      // [512,32,1024]
  float* out = (float*)d_out;

  const size_t GATHER = (size_t)NB * NK * NL * NH;  // 268435456 floats
  float* top_sim = out + GATHER;                    // final output tail [1024*8]

  // Scratch carved from the gather region of d_out (stream order serializes
  // producers/consumers):
  //  - sim / qinv / kinv at the front: consumed by topk before gather overwrites.
  //  - idx in the LAST 8192 floats: lies only inside slice bk=8191, written by
  //    gather_last (single block, read-then-barrier-then-write).
  float* sim = out;                             // [1024*512] = 2 MiB
  float* qinv = out + (size_t)NB * NP;          // [1024]
  float* kinv = qinv + NB;                      // [512]
  int* idx = (int*)(out + GATHER - (size_t)NB * NK);  // [8192] ints

  norms_kernel<<<(NB + NP) / 4, 256, 0, stream>>>(querys, prompts_key, qinv, kinv);

  dim3 gsim(NB / 32, NP / 32);  // 32 x 16
  sim_kernel<<<gsim, 256, 0, stream>>>(querys, prompts_key, qinv, kinv, sim);

  topk_kernel<<<NB / 4, 256, 0, stream>>>(sim, top_sim, idx);

  gather_main<<<NB * NK - 1, 256, 0, stream>>>(prompts, idx, out);
  gather_last<<<1, 256, 0, stream>>>(prompts, idx, out);
}

// Round 3
// 298.899 us; speedup vs baseline: 1.2413x; 1.2146x over previous
//
#include <hip/hip_runtime.h>
#include <math.h>

#define NB 1024      // batch (queries)
#define NP 512       // pool size
#define NH 1024      // hidden
#define NK 8         // topk
#define NL 32        // pre_seq_len
#define NBK (NB * NK)
#define SLICE (NL * NH)   // floats per output slice (32768 = 128 KB)
#define EPSF 1e-8f

typedef float f32x4 __attribute__((ext_vector_type(4)));

// ---------------- Kernel 1: inverse norms (1/max(||row||, eps)) ----------------
__global__ __launch_bounds__(256) void norms_kernel(
    const float* __restrict__ q, const float* __restrict__ pk,
    float* __restrict__ qinv, float* __restrict__ kinv) {
  int row = blockIdx.x * 4 + (threadIdx.x >> 6);
  int lane = threadIdx.x & 63;
  const float* src;
  float* dst;
  if (row < NB) {
    src = q + (size_t)row * NH;
    dst = qinv + row;
  } else {
    int r = row - NB;
    if (r >= NP) return;
    src = pk + (size_t)r * NH;
    dst = kinv + r;
  }
  const float4* v = (const float4*)src;
  float s = 0.f;
#pragma unroll
  for (int i = 0; i < (NH / 4) / 64; ++i) {
    float4 x = v[lane + i * 64];
    s += x.x * x.x + x.y * x.y + x.z * x.z + x.w * x.w;
  }
#pragma unroll
  for (int off = 32; off; off >>= 1) s += __shfl_xor(s, off);
  if (lane == 0) *dst = 1.f / fmaxf(sqrtf(s), EPSF);
}

// ---------------- Kernel 2: sim = qn . kn^T, tiled fp32 GEMM ----------------
__global__ __launch_bounds__(256) void sim_kernel(
    const float* __restrict__ q, const float* __restrict__ pk,
    const float* __restrict__ qinv, const float* __restrict__ kinv,
    float* __restrict__ sim) {
  __shared__ float As[32][34];  // [k][m] transposed; stride 34
  __shared__ float Bs[32][34];  // [k][n]
  const int bm = blockIdx.x;
  const int bn = blockIdx.y;
  const int tid = threadIdx.x;
  const int tx = tid & 15;
  const int ty = tid >> 4;
  const int lrow = tid >> 3;
  const int lcol = (tid & 7) * 4;

  float acc00 = 0.f, acc01 = 0.f, acc10 = 0.f, acc11 = 0.f;

  const float* qrow = q + (size_t)(bm * 32 + lrow) * NH + lcol;
  const float* krow = pk + (size_t)(bn * 32 + lrow) * NH + lcol;

  for (int kt = 0; kt < NH; kt += 32) {
    float4 a = *(const float4*)(qrow + kt);
    float4 b = *(const float4*)(krow + kt);
    __syncthreads();
    As[lcol + 0][lrow] = a.x; As[lcol + 1][lrow] = a.y;
    As[lcol + 2][lrow] = a.z; As[lcol + 3][lrow] = a.w;
    Bs[lcol + 0][lrow] = b.x; Bs[lcol + 1][lrow] = b.y;
    Bs[lcol + 2][lrow] = b.z; Bs[lcol + 3][lrow] = b.w;
    __syncthreads();
#pragma unroll
    for (int k = 0; k < 32; ++k) {
      float2 a01 = *(const float2*)&As[k][2 * ty];
      float2 b01 = *(const float2*)&Bs[k][2 * tx];
      acc00 += a01.x * b01.x; acc01 += a01.x * b01.y;
      acc10 += a01.y * b01.x; acc11 += a01.y * b01.y;
    }
  }

  const int r0 = bm * 32 + 2 * ty;
  const int c0 = bn * 32 + 2 * tx;
  const float qi0 = qinv[r0], qi1 = qinv[r0 + 1];
  const float ki0 = kinv[c0], ki1 = kinv[c0 + 1];
  sim[(size_t)(r0 + 0) * NP + c0 + 0] = acc00 * qi0 * ki0;
  sim[(size_t)(r0 + 0) * NP + c0 + 1] = acc01 * qi0 * ki1;
  sim[(size_t)(r0 + 1) * NP + c0 + 0] = acc10 * qi1 * ki0;
  sim[(size_t)(r0 + 1) * NP + c0 + 1] = acc11 * qi1 * ki1;
}

// ---------------- Kernel 3: per-row top-8 (sorted desc, tie -> lower index) ----------------
__global__ __launch_bounds__(256) void topk_kernel(
    const float* __restrict__ sim, float* __restrict__ top_sim, int* __restrict__ top_idx) {
  int row = blockIdx.x * 4 + (threadIdx.x >> 6);
  int lane = threadIdx.x & 63;
  if (row >= NB) return;

  float vals[NP / 64];
#pragma unroll
  for (int i = 0; i < NP / 64; ++i) vals[i] = sim[(size_t)row * NP + lane + i * 64];

  for (int t = 0; t < NK; ++t) {
    float bv = vals[0];
    int bi = 0;
#pragma unroll
    for (int i = 1; i < NP / 64; ++i) {
      if (vals[i] > bv) { bv = vals[i]; bi = i; }
    }
    float v = bv;
    int p = lane + bi * 64;
#pragma unroll
    for (int off = 32; off; off >>= 1) {
      float ov = __shfl_xor(v, off);
      int op = __shfl_xor(p, off);
      if (ov > v || (ov == v && op < p)) { v = ov; p = op; }
    }
    if (lane == 0) {
      top_sim[row * NK + t] = v;
      top_idx[row * NK + t] = p;
    }
    if ((p & 63) == lane) {
      int wi = p >> 6;
#pragma unroll
      for (int i = 0; i < NP / 64; ++i)
        if (i == wi) vals[i] = -INFINITY;
    }
  }
}

// ---------------- Kernel 3.5: counting-sort permutation of 0..8191 by idx[] ----------------
// Single block, 512 threads. order[] = slot ids grouped by pool index p.
__global__ __launch_bounds__(512) void sortperm_kernel(
    const int* __restrict__ idx, int* __restrict__ order) {
  __shared__ int hist[NP];
  __shared__ int offs[NP];
  const int t = threadIdx.x;
  hist[t] = 0;
  __syncthreads();
  for (int i = t; i < NBK; i += 512) atomicAdd(&hist[idx[i]], 1);
  __syncthreads();
  int sum = 0;
  for (int i = 0; i < t; ++i) sum += hist[i];  // broadcast reads, 512 bins
  offs[t] = sum;
  __syncthreads();
  for (int i = t; i < NBK; i += 512) {
    int p = idx[i];
    int pos = atomicAdd(&offs[p], 1);
    order[pos] = i;  // any order within a bin is fine
  }
}

// ---------------- Kernel 4: gather in p-sorted dispatch order ----------------
// Block s copies output slice j=order[s]; consumers of the same pool slice are
// adjacent in s -> concurrent -> one HBM miss per pool line, rest L2/L3 hits.
__global__ __launch_bounds__(256) void gather_sorted(
    const float* __restrict__ prompts, const int* __restrict__ idx,
    const int* __restrict__ order, float* __restrict__ out, int skip_slice) {
  const int j = order[blockIdx.x];
  if (j == skip_slice) return;  // that slice holds scratch; copied by tail kernel
  const int p = idx[j];
  const f32x4* __restrict__ src = (const f32x4*)(prompts + (size_t)p * SLICE);
  f32x4* __restrict__ dst = (f32x4*)(out + (size_t)j * SLICE);
  const int t = threadIdx.x;
#pragma unroll
  for (int i = 0; i < (SLICE / 4) / 256; ++i) {
    f32x4 v = src[t + i * 256];
    __builtin_nontemporal_store(v, &dst[t + i * 256]);
  }
}

// ---------------- Kernel 4b (fallback only): copy the scratch-holding slice ----------------
__global__ __launch_bounds__(256) void gather_tail(
    const float* __restrict__ prompts, const int* __restrict__ idx,
    float* __restrict__ out, int j) {
  const int p = idx[j];
  __syncthreads();  // everyone has read idx before we overwrite its storage
  const f32x4* __restrict__ src = (const f32x4*)(prompts + (size_t)p * SLICE);
  f32x4* __restrict__ dst = (f32x4*)(out + (size_t)j * SLICE);
  const int t = threadIdx.x;
#pragma unroll
  for (int i = 0; i < (SLICE / 4) / 256; ++i) {
    f32x4 v = src[t + i * 256];
    __builtin_nontemporal_store(v, &dst[t + i * 256]);
  }
}

extern "C" void kernel_launch(void* const* d_in, const int* in_sizes, int n_in,
                              void* d_out, int out_size, void* d_ws, size_t ws_size,
                              hipStream_t stream) {
  const float* querys = (const float*)d_in[0];       // [1024,1024]
  const float* prompts_key = (const float*)d_in[1];  // [512,1024]
  const float* prompts = (const float*)d_in[2];      // [512,32,1024]
  float* out = (float*)d_out;

  const size_t GATHER = (size_t)NBK * SLICE;  // 268435456 floats
  float* top_sim = out + GATHER;              // real output tail [8192]

  // sim / norms scratch at the FRONT of out: fully consumed by topk before
  // gather overwrites those slices (stream order serializes kernels).
  float* sim = out;                      // [1024*512] = 2 MiB (slices 0..15)
  float* qinv = out + (size_t)NB * NP;   // [1024]
  float* kinv = qinv + NB;               // [512]

  // idx[8192] + order[8192] (64 KB): prefer d_ws; else carve from the first
  // 64 KB of output slice 8190 (gather then skips j==8190; tail kernel does it).
  int* idx;
  int* order;
  int skip_slice;
  if (ws_size >= 2 * NBK * sizeof(int)) {
    idx = (int*)d_ws;
    order = idx + NBK;
    skip_slice = -1;  // no slice holds scratch
  } else {
    idx = (int*)(out + (size_t)(NBK - 2) * SLICE);  // start of slice 8190
    order = idx + NBK;
    skip_slice = NBK - 2;
  }

  norms_kernel<<<(NB + NP) / 4, 256, 0, stream>>>(querys, prompts_key, qinv, kinv);

  dim3 gsim(NB / 32, NP / 32);
  sim_kernel<<<gsim, 256, 0, stream>>>(querys, prompts_key, qinv, kinv, sim);

  topk_kernel<<<NB / 4, 256, 0, stream>>>(sim, top_sim, idx);

  sortperm_kernel<<<1, 512, 0, stream>>>(idx, order);

  gather_sorted<<<NBK, 256, 0, stream>>>(prompts, idx, order, out, skip_slice);

  if (skip_slice >= 0) {
    gather_tail<<<1, 256, 0, stream>>>(prompts, idx, out, skip_slice);
  }
}